// Round 14
// baseline (61.155 us; speedup 1.0000x reference)
//
#include <hip/hip_runtime.h>
#include <hip/hip_bf16.h>

// kernel[i,j] = | prod_{k<16} cos((x[i,k]-y[j,k])/2) |   (f32 in, f32 out)
//
// MFMA formulation (verified r10-r13, absmax 0.00390625): per wire-pair
//   cos(a)cos(b) = 1/2[cos(Rm-Cm) + cos(Rp-Cp)]  -> 4-term separable dot;
// quad (pair x pair) = 16-term dot  Q_q = sum_t A_q[i,t] B_q[j,t];
// out = |Q0 Q1 Q2 Q3|. One mfma_f32_32x32x16_bf16 per quad (K=16 exact).
// Orientation (r12 vs r13 lesson): A=row factors, B=col factors so D's LANE
// dim = output column (contiguous 128 B store segments). reg r -> row
// (r&3)+8*(r>>2)+4*(lane>>5), col = lane&31  [m74/m101, r12-validated].
//
// r14 vs r13 (60.59): tile 64x64 -> 128x128 (256 blocks, 1 blk/CU).
// Staging recompute halves (total staging ~ nm(1/BR+1/BC)); A-frags reused
// across 4 col-blocks (frag b128 per wave-strip 32 -> 20). Stores unchanged
// (NT, lane-contiguous cols). Staging: 1 thread/unit, 256 units/block.

constexpr int D = 16;
constexpr int RSTR = 72;   // LDS row stride in shorts (144 B, 16B-aligned)

typedef short  bf16x8 __attribute__((ext_vector_type(8)));
typedef float  f32x16 __attribute__((ext_vector_type(16)));

static __device__ inline unsigned int pk2(float a, float b) {
    __hip_bfloat16 ha = __float2bfloat16(a);
    __hip_bfloat16 hb = __float2bfloat16(b);
    unsigned short ua, ub;
    __builtin_memcpy(&ua, &ha, 2);
    __builtin_memcpy(&ub, &hb, 2);
    return (unsigned int)ua | ((unsigned int)ub << 16);
}

__global__ __launch_bounds__(256)
void qkern(const float* __restrict__ x, const float* __restrict__ y,
           float* __restrict__ out, int m) {
    __shared__ unsigned short Al[128 * RSTR];  // row terms: 128 rows x 64 bf16
    __shared__ unsigned short Bl[128 * RSTR];  // col terms: 128 cols x 64 bf16

    const int tid   = threadIdx.x;
    const int row0b = blockIdx.x * 128;
    const int col0b = blockIdx.y * 128;

    // ---- Stage: 256 units (128 rows + 128 cols), 1 thread/unit. ----
    {
        const int u = tid;
        const bool isrow = (u < 128);
        const float* src = isrow ? (x + (size_t)(row0b + u) * D)
                                 : (y + (size_t)(col0b + (u - 128)) * D);
        unsigned short* dst = isrow ? (Al + (size_t)u * RSTR)
                                    : (Bl + (size_t)(u - 128) * RSTR);
        const float scale = isrow ? 0.5f : 1.0f;   // 1/2 per pair, rows only

        float f[8][4];
#pragma unroll
        for (int p = 0; p < 8; ++p) {
            const float a0 = src[2 * p], a1 = src[2 * p + 1];
            float sm, cm, sp, cp;
            __sincosf(0.5f * (a0 - a1), &sm, &cm);
            __sincosf(0.5f * (a0 + a1), &sp, &cp);
            f[p][0] = scale * cm; f[p][1] = scale * sm;
            f[p][2] = scale * cp; f[p][3] = scale * sp;
        }
#pragma unroll
        for (int q = 0; q < 4; ++q) {
            const float* fa = f[2 * q];
            const float* fb = f[2 * q + 1];
            uint4 lo, hi;
            lo.x = pk2(fa[0] * fb[0], fa[0] * fb[1]);
            lo.y = pk2(fa[0] * fb[2], fa[0] * fb[3]);
            lo.z = pk2(fa[1] * fb[0], fa[1] * fb[1]);
            lo.w = pk2(fa[1] * fb[2], fa[1] * fb[3]);
            hi.x = pk2(fa[2] * fb[0], fa[2] * fb[1]);
            hi.y = pk2(fa[2] * fb[2], fa[2] * fb[3]);
            hi.z = pk2(fa[3] * fb[0], fa[3] * fb[1]);
            hi.w = pk2(fa[3] * fb[2], fa[3] * fb[3]);
            *(uint4*)(dst + q * 16)     = lo;
            *(uint4*)(dst + q * 16 + 8) = hi;
        }
    }
    __syncthreads();

    // ---- MFMA: wave = 32x128 strip (4 tiles of 32x32, shared A-frags). ----
    const int wave = tid >> 6;
    const int lane = tid & 63;
    const int l31  = lane & 31;
    const int kh   = lane >> 5;          // k-half: 0 -> k0..7, 1 -> k8..15
    const int rw   = wave * 32;          // strip row base within tile

    const f32x16 zc = {0.f};

    bf16x8 af[4];
#pragma unroll
    for (int q = 0; q < 4; ++q)
        af[q] = *(const bf16x8*)(Al + (size_t)(rw + l31) * RSTR + q * 16 + kh * 8);

#pragma unroll
    for (int cb = 0; cb < 4; ++cb) {
        const int cw = cb * 32;
        f32x16 prod;
        {
            const bf16x8 b0 = *(const bf16x8*)(Bl + (size_t)(cw + l31) * RSTR + kh * 8);
            prod = __builtin_amdgcn_mfma_f32_32x32x16_bf16(af[0], b0, zc, 0, 0, 0);
        }
#pragma unroll
        for (int q = 1; q < 4; ++q) {
            const bf16x8 bq = *(const bf16x8*)(Bl + (size_t)(cw + l31) * RSTR + q * 16 + kh * 8);
            const f32x16 acc = __builtin_amdgcn_mfma_f32_32x32x16_bf16(af[q], bq, zc, 0, 0, 0);
            prod *= acc;
        }

        // Epilogue: reg r -> row = rw + (r&3)+8*(r>>2)+4*kh; col = cw + l31.
        float* base = out + (size_t)(row0b + rw + 4 * kh) * m + col0b + cw + l31;
#pragma unroll
        for (int r = 0; r < 16; ++r) {
            const int row_off = (r & 3) + 8 * (r >> 2);
            __builtin_nontemporal_store(fabsf(prod[r]), base + (size_t)row_off * m);
        }
    }
}

extern "C" void kernel_launch(void* const* d_in, const int* in_sizes, int n_in,
                              void* d_out, int out_size, void* d_ws, size_t ws_size,
                              hipStream_t stream) {
    const float* x = (const float*)d_in[0];
    const float* y = (const float*)d_in[1];
    float* out = (float*)d_out;
    const int n = in_sizes[0] / D;   // 2048
    const int m = in_sizes[1] / D;   // 2048

    dim3 grid(n / 128, m / 128);     // 16 x 16 = 256 blocks -> 1 blk/CU
    qkern<<<grid, 256, 0, stream>>>(x, y, out, m);
}